// Round 4
// baseline (68.269 us; speedup 1.0000x reference)
//
#include <hip/hip_runtime.h>

#define HW 16384   // H*W
#define NH 4
#define HD 16

// ---------------- Kernel 1: QKV projection (LDS-staged x, SGPR weights) ------
// grid: dim3(3, 256, 2) = (slice, strip, batch); block 256 = 64px x 4 osub
// Outputs qT,kT,vT: layout [((b*4+h)*HW + p)*16 + d], q pre-scaled by 0.25.
__global__ __launch_bounds__(256) void qkv_kernel(
    const float* __restrict__ x, const float* __restrict__ w,
    const float* __restrict__ bias, float* __restrict__ qT,
    float* __restrict__ kT, float* __restrict__ vT)
{
  __shared__ float xs[64][72];     // pad 64->72 breaks write bank aliasing
  int slice = blockIdx.x;          // 0..2
  int p0    = blockIdx.y * 64;
  int b     = blockIdx.z;
  int t     = threadIdx.x;

  {  // stage x strip [64ch][64px]
    int c = t >> 2, f4 = t & 3;
    const float4* src = (const float4*)(x + (size_t)(b * 64 + c) * HW + p0);
    float4* dst = (float4*)(&xs[c][0]);
#pragma unroll
    for (int k2 = 0; k2 < 4; ++k2) dst[f4 * 4 + k2] = src[f4 * 4 + k2];
  }
  __syncthreads();

  int px = t & 63;
  // readfirstlane -> SGPR -> weight/bias addresses provably uniform -> s_load
  int wv  = __builtin_amdgcn_readfirstlane(t >> 6);
  int o16 = slice * 4 + wv;        // 0..11
  int o0  = o16 * 16;
  int tsel = o16 >> 2;             // 0=q,1=k,2=v
  int h    = o16 & 3;

  float acc[16];
#pragma unroll
  for (int d = 0; d < 16; ++d) acc[d] = bias[o0 + d];

  for (int c4 = 0; c4 < 16; ++c4) {
    float a0 = xs[c4 * 4 + 0][px];
    float a1 = xs[c4 * 4 + 1][px];
    float a2 = xs[c4 * 4 + 2][px];
    float a3 = xs[c4 * 4 + 3][px];
#pragma unroll
    for (int d = 0; d < 16; ++d) {
      const float* wr = w + (o0 + d) * 64 + c4 * 4;
      acc[d] = fmaf(wr[0], a0, acc[d]);
      acc[d] = fmaf(wr[1], a1, acc[d]);
      acc[d] = fmaf(wr[2], a2, acc[d]);
      acc[d] = fmaf(wr[3], a3, acc[d]);
    }
  }
  if (tsel == 0) {
#pragma unroll
    for (int d = 0; d < 16; ++d) acc[d] *= 0.25f;   // hd^-0.5
  }
  float* dst = (tsel == 0) ? qT : ((tsel == 1) ? kT : vT);
  float4* dp = (float4*)(dst + ((size_t)(b * NH + h) * HW + p0 + px) * HD);
  dp[0] = make_float4(acc[0], acc[1], acc[2], acc[3]);
  dp[1] = make_float4(acc[4], acc[5], acc[6], acc[7]);
  dp[2] = make_float4(acc[8], acc[9], acc[10], acc[11]);
  dp[3] = make_float4(acc[12], acc[13], acc[14], acc[15]);
}

// ---------------- Kernel 2: tiled neighborhood attention ---------------------
// grid: dim3(64, 4, 2) = (tile, head, batch); block 256 = 16x16 pixel tile.
// Pixel-major swizzled LDS, b128 reads, K-phase then V-phase through one buffer.
// Swizzle: byte = (px<<6) ^ ((((px&7)^d4))<<4)  (bijective; bank-group
// bg = ((px&1)<<2|d4)^(px&7) covers all 8 groups uniformly for writes & reads)

__device__ __forceinline__ float4* swzp(float* buf, int px, int d4) {
  int off = (px << 6) ^ (((px & 7) ^ d4) << 4);
  return (float4*)((char*)buf + off);
}
__device__ __forceinline__ const float4* swzpc(const float* buf, int px, int d4) {
  int off = (px << 6) ^ (((px & 7) ^ d4) << 4);
  return (const float4*)((const char*)buf + off);
}

__global__ __launch_bounds__(256) void attn_kernel(
    const float* __restrict__ qT, const float* __restrict__ kT,
    const float* __restrict__ vT, const float* __restrict__ rb,
    float* __restrict__ attO)
{
  __shared__ float KV[484 * 16];   // 30.25 KB, one halo (K, then V)
  __shared__ float rbl[169];

  int tile = blockIdx.x;           // 0..63 (8x8 tiles of 16x16)
  int h    = blockIdx.y;
  int b    = blockIdx.z;
  int tx0  = (tile & 7) * 16;
  int ty0  = (tile >> 3) * 16;
  int oy   = ty0 - 3, ox = tx0 - 3;   // halo origin (may be negative)
  int t    = threadIdx.x;

  size_t base = (size_t)(b * NH + h) * HW;

  if (t < 169) rbl[t] = rb[t * NH + h];

  // ---- stage K halo (484 px * 4 float4) ----
  for (int idx = t; idx < 1936; idx += 256) {
    int pxi = idx >> 2, d4 = idx & 3;
    int r = pxi / 22, c = pxi % 22;
    int ra = oy + r; ra = ra < 0 ? 0 : (ra > 127 ? 127 : ra);
    int ca = ox + c; ca = ca < 0 ? 0 : (ca > 127 ? 127 : ca);
    size_t gp = (base + (size_t)ra * 128 + ca) * HD;
    *swzp(KV, pxi, d4) = ((const float4*)(kT + gp))[d4];
  }

  int lx = t & 15, ly = t >> 4;
  int y = ty0 + ly, xc = tx0 + lx;
  int sy = y - 3;  sy = sy < 0 ? 0 : (sy > 121 ? 121 : sy);
  int sx = xc - 3; sx = sx < 0 ? 0 : (sx > 121 ? 121 : sx);
  int li0 = sy - oy, lj0 = sx - ox;      // local window origin in halo
  int ih = y - sy, iw = xc - sx;         // bias offsets

  float qd[16];
  {
    const float4* qp = (const float4*)(qT + (base + (size_t)y * 128 + xc) * HD);
#pragma unroll
    for (int k = 0; k < 4; ++k) {
      float4 v = qp[k];
      qd[4 * k + 0] = v.x; qd[4 * k + 1] = v.y;
      qd[4 * k + 2] = v.z; qd[4 * k + 3] = v.w;
    }
  }

  __syncthreads();

  // ---- QK^T over window (b128 LDS reads) ----
  float lg[49];
#pragma unroll
  for (int i = 0; i < 7; ++i) {
#pragma unroll
    for (int j = 0; j < 7; ++j) {
      int px = (li0 + i) * 22 + (lj0 + j);
      float4 k0 = *swzpc(KV, px, 0);
      float4 k1 = *swzpc(KV, px, 1);
      float4 k2 = *swzpc(KV, px, 2);
      float4 k3 = *swzpc(KV, px, 3);
      float d;
      d = fmaf(qd[0], k0.x, rbl[(ih + i) * 13 + (iw + j)]);
      d = fmaf(qd[1], k0.y, d);  d = fmaf(qd[2], k0.z, d);
      d = fmaf(qd[3], k0.w, d);  d = fmaf(qd[4], k1.x, d);
      d = fmaf(qd[5], k1.y, d);  d = fmaf(qd[6], k1.z, d);
      d = fmaf(qd[7], k1.w, d);  d = fmaf(qd[8], k2.x, d);
      d = fmaf(qd[9], k2.y, d);  d = fmaf(qd[10], k2.z, d);
      d = fmaf(qd[11], k2.w, d); d = fmaf(qd[12], k3.x, d);
      d = fmaf(qd[13], k3.y, d); d = fmaf(qd[14], k3.z, d);
      d = fmaf(qd[15], k3.w, d);
      lg[i * 7 + j] = d;
    }
  }

  // ---- softmax ----
  float mx = lg[0];
#pragma unroll
  for (int k = 1; k < 49; ++k) mx = fmaxf(mx, lg[k]);
  float s = 0.f;
#pragma unroll
  for (int k = 0; k < 49; ++k) { lg[k] = __expf(lg[k] - mx); s += lg[k]; }
  float inv = 1.f / s;

  // ---- stage V halo into the same buffer ----
  __syncthreads();
  for (int idx = t; idx < 1936; idx += 256) {
    int pxi = idx >> 2, d4 = idx & 3;
    int r = pxi / 22, c = pxi % 22;
    int ra = oy + r; ra = ra < 0 ? 0 : (ra > 127 ? 127 : ra);
    int ca = ox + c; ca = ca < 0 ? 0 : (ca > 127 ? 127 : ca);
    size_t gp = (base + (size_t)ra * 128 + ca) * HD;
    *swzp(KV, pxi, d4) = ((const float4*)(vT + gp))[d4];
  }
  __syncthreads();

  // ---- PV over window ----
  float4 o0 = make_float4(0,0,0,0), o1 = o0, o2 = o0, o3 = o0;
#pragma unroll
  for (int i = 0; i < 7; ++i) {
#pragma unroll
    for (int j = 0; j < 7; ++j) {
      int px = (li0 + i) * 22 + (lj0 + j);
      float p = lg[i * 7 + j];
      float4 v0 = *swzpc(KV, px, 0);
      float4 v1 = *swzpc(KV, px, 1);
      float4 v2 = *swzpc(KV, px, 2);
      float4 v3 = *swzpc(KV, px, 3);
      o0.x = fmaf(p, v0.x, o0.x); o0.y = fmaf(p, v0.y, o0.y);
      o0.z = fmaf(p, v0.z, o0.z); o0.w = fmaf(p, v0.w, o0.w);
      o1.x = fmaf(p, v1.x, o1.x); o1.y = fmaf(p, v1.y, o1.y);
      o1.z = fmaf(p, v1.z, o1.z); o1.w = fmaf(p, v1.w, o1.w);
      o2.x = fmaf(p, v2.x, o2.x); o2.y = fmaf(p, v2.y, o2.y);
      o2.z = fmaf(p, v2.z, o2.z); o2.w = fmaf(p, v2.w, o2.w);
      o3.x = fmaf(p, v3.x, o3.x); o3.y = fmaf(p, v3.y, o3.y);
      o3.z = fmaf(p, v3.z, o3.z); o3.w = fmaf(p, v3.w, o3.w);
    }
  }

  // write channel-major (pre-projection) into attO (= d_out, overwritten later)
  size_t op = (size_t)y * 128 + xc;
  float* ob = attO + (size_t)b * 64 * HW + (size_t)h * 16 * HW + op;
  ob[0 * HW] = o0.x * inv;  ob[1 * HW] = o0.y * inv;
  ob[2 * HW] = o0.z * inv;  ob[3 * HW] = o0.w * inv;
  ob[4 * HW] = o1.x * inv;  ob[5 * HW] = o1.y * inv;
  ob[6 * HW] = o1.z * inv;  ob[7 * HW] = o1.w * inv;
  ob[8 * HW] = o2.x * inv;  ob[9 * HW] = o2.y * inv;
  ob[10 * HW] = o2.z * inv; ob[11 * HW] = o2.w * inv;
  ob[12 * HW] = o3.x * inv; ob[13 * HW] = o3.y * inv;
  ob[14 * HW] = o3.z * inv; ob[15 * HW] = o3.w * inv;
}

// ---------------- Kernel 3: output projection (in-place over d_out) ----------
// grid: dim3(256, 2) = (strip, batch); block 256 = 64px x 4 og.
// Reads its own 64x64 strip of attO (=d_out) into LDS, syncs, overwrites it.
__global__ __launch_bounds__(256) void proj_kernel(
    const float* __restrict__ pw, const float* __restrict__ pb,
    float* __restrict__ out)
{
  __shared__ float as[64][72];
  int p0 = blockIdx.x * 64;
  int b  = blockIdx.y;
  int t  = threadIdx.x;

  {
    int c = t >> 2, f4 = t & 3;
    const float4* src = (const float4*)(out + (size_t)(b * 64 + c) * HW + p0);
    float4* dst = (float4*)(&as[c][0]);
#pragma unroll
    for (int k2 = 0; k2 < 4; ++k2) dst[f4 * 4 + k2] = src[f4 * 4 + k2];
  }
  __syncthreads();

  int px = t & 63;
  int og = __builtin_amdgcn_readfirstlane(t >> 6);   // uniform -> s_load weights
  float acc[16];
#pragma unroll
  for (int oo = 0; oo < 16; ++oo) acc[oo] = pb[og * 16 + oo];

  for (int c4 = 0; c4 < 16; ++c4) {
    float a0 = as[c4 * 4 + 0][px];
    float a1 = as[c4 * 4 + 1][px];
    float a2 = as[c4 * 4 + 2][px];
    float a3 = as[c4 * 4 + 3][px];
#pragma unroll
    for (int oo = 0; oo < 16; ++oo) {
      const float* wr = pw + (og * 16 + oo) * 64 + c4 * 4;
      acc[oo] = fmaf(wr[0], a0, acc[oo]);
      acc[oo] = fmaf(wr[1], a1, acc[oo]);
      acc[oo] = fmaf(wr[2], a2, acc[oo]);
      acc[oo] = fmaf(wr[3], a3, acc[oo]);
    }
  }
#pragma unroll
  for (int oo = 0; oo < 16; ++oo)
    out[((size_t)b * 64 + og * 16 + oo) * HW + p0 + px] = acc[oo];
}

extern "C" void kernel_launch(void* const* d_in, const int* in_sizes, int n_in,
                              void* d_out, int out_size, void* d_ws, size_t ws_size,
                              hipStream_t stream) {
  const float* x      = (const float*)d_in[0];
  const float* qkv_w  = (const float*)d_in[1];
  const float* qkv_b  = (const float*)d_in[2];
  const float* proj_w = (const float*)d_in[3];
  const float* proj_b = (const float*)d_in[4];
  const float* rb     = (const float*)d_in[5];
  float* out = (float*)d_out;

  const size_t TSZ = (size_t)2 * NH * HW * HD;   // 2,097,152 floats each
  float* qT = (float*)d_ws;
  float* kT = qT + TSZ;
  float* vT = kT + TSZ;

  qkv_kernel<<<dim3(3, 256, 2), 256, 0, stream>>>(x, qkv_w, qkv_b, qT, kT, vT);
  attn_kernel<<<dim3(64, NH, 2), 256, 0, stream>>>(qT, kT, vT, rb, out);
  proj_kernel<<<dim3(256, 2), 256, 0, stream>>>(proj_w, proj_b, out);
}